// Round 5
// baseline (71.046 us; speedup 1.0000x reference)
//
#include <hip/hip_runtime.h>

#define S_DIM 4096
#define C_DIM 2048      // C1 == C2
#define N_DIM 1024
#define K_DIM 4096      // C1 + C2

#define BM 128
#define BN 128
#define BK 32
#define NT (K_DIM / BK)         // 128 K-steps
#define TILE_BYTES 16384        // (128 A rows + 128 B rows) * 64 B
#define NBUF 8                  // 128 KB LDS, depth-8 ring

typedef __attribute__((ext_vector_type(8))) short bf16x8;
typedef __attribute__((ext_vector_type(4))) float f32x4;

__device__ static inline unsigned short f2bf(float f) {
    unsigned int u = __float_as_uint(f);
    u += 0x7FFFu + ((u >> 16) & 1u);
    return (unsigned short)(u >> 16);
}

// ---------------- exp + cast to bf16 for A (both ll sources, one launch) ----------------
__global__ void exp_ll_kernel(const float* __restrict__ ll1,
                              const float* __restrict__ ll2,
                              unsigned short* __restrict__ A) {
    const int total4 = S_DIM * C_DIM / 4;
    int stride = gridDim.x * blockDim.x;
    for (int i = blockIdx.x * blockDim.x + threadIdx.x; i < total4; i += stride) {
        int e = i << 2;
        int r = e >> 11;          // src cols = 2048
        int c = e & 2047;
        size_t dst = ((size_t)r << 12) + c;
        float4 v = *reinterpret_cast<const float4*>(ll1 + e);
        ushort4 o;
        o.x = f2bf(__expf(v.x)); o.y = f2bf(__expf(v.y));
        o.z = f2bf(__expf(v.z)); o.w = f2bf(__expf(v.w));
        *reinterpret_cast<ushort4*>(A + dst) = o;
        float4 u = *reinterpret_cast<const float4*>(ll2 + e);
        ushort4 p;
        p.x = f2bf(__expf(u.x)); p.y = f2bf(__expf(u.y));
        p.z = f2bf(__expf(u.z)); p.w = f2bf(__expf(u.w));
        *reinterpret_cast<ushort4*>(A + dst + C_DIM) = p;
    }
}

// ---------------- w: exp->B (bf16) AND per-row logsumexp, fused ----------------
__global__ void w_kernel(const float* __restrict__ w1,
                         const float* __restrict__ w2,
                         unsigned short* __restrict__ B,
                         float* __restrict__ lz) {
    const int n = blockIdx.x;
    const int tid = threadIdx.x;          // 0..255
    const int lane = tid & 63, wv = tid >> 6;
    const float* r1 = w1 + ((size_t)n << 11);
    const float* r2 = w2 + ((size_t)n << 11);
    float4 v0 = *reinterpret_cast<const float4*>(r1 + tid * 8);
    float4 v1 = *reinterpret_cast<const float4*>(r1 + tid * 8 + 4);
    float4 u0 = *reinterpret_cast<const float4*>(r2 + tid * 8);
    float4 u1 = *reinterpret_cast<const float4*>(r2 + tid * 8 + 4);

    float mx = fmaxf(fmaxf(fmaxf(v0.x, v0.y), fmaxf(v0.z, v0.w)),
                     fmaxf(fmaxf(v1.x, v1.y), fmaxf(v1.z, v1.w)));
    mx = fmaxf(mx, fmaxf(fmaxf(fmaxf(u0.x, u0.y), fmaxf(u0.z, u0.w)),
                          fmaxf(fmaxf(u1.x, u1.y), fmaxf(u1.z, u1.w))));
    #pragma unroll
    for (int off = 32; off > 0; off >>= 1) mx = fmaxf(mx, __shfl_xor(mx, off));
    __shared__ float red[4];
    if (lane == 0) red[wv] = mx;
    __syncthreads();
    mx = fmaxf(fmaxf(red[0], red[1]), fmaxf(red[2], red[3]));

    float s = __expf(v0.x - mx) + __expf(v0.y - mx) + __expf(v0.z - mx) + __expf(v0.w - mx)
            + __expf(v1.x - mx) + __expf(v1.y - mx) + __expf(v1.z - mx) + __expf(v1.w - mx)
            + __expf(u0.x - mx) + __expf(u0.y - mx) + __expf(u0.z - mx) + __expf(u0.w - mx)
            + __expf(u1.x - mx) + __expf(u1.y - mx) + __expf(u1.z - mx) + __expf(u1.w - mx);
    #pragma unroll
    for (int off = 32; off > 0; off >>= 1) s += __shfl_xor(s, off);
    __shared__ float red2[4];
    if (lane == 0) red2[wv] = s;
    __syncthreads();
    if (tid == 0)
        lz[n] = mx + __logf(red2[0] + red2[1] + red2[2] + red2[3]);

    unsigned short* brow = B + ((size_t)n << 12);
    ushort4 o;
    o.x = f2bf(__expf(v0.x)); o.y = f2bf(__expf(v0.y));
    o.z = f2bf(__expf(v0.z)); o.w = f2bf(__expf(v0.w));
    *reinterpret_cast<ushort4*>(brow + tid * 8) = o;
    o.x = f2bf(__expf(v1.x)); o.y = f2bf(__expf(v1.y));
    o.z = f2bf(__expf(v1.z)); o.w = f2bf(__expf(v1.w));
    *reinterpret_cast<ushort4*>(brow + tid * 8 + 4) = o;
    o.x = f2bf(__expf(u0.x)); o.y = f2bf(__expf(u0.y));
    o.z = f2bf(__expf(u0.z)); o.w = f2bf(__expf(u0.w));
    *reinterpret_cast<ushort4*>(brow + C_DIM + tid * 8) = o;
    o.x = f2bf(__expf(u1.x)); o.y = f2bf(__expf(u1.y));
    o.z = f2bf(__expf(u1.z)); o.w = f2bf(__expf(u1.w));
    *reinterpret_cast<ushort4*>(brow + C_DIM + tid * 8 + 4) = o;
}

// ------- bf16 MFMA GEMM: C = A*B^T, log-epilogue, depth-8 ring + reg-frag pipeline -------
typedef const unsigned int __attribute__((address_space(1)))* gas_ptr;
typedef unsigned int __attribute__((address_space(3)))* las_ptr;

__global__ __launch_bounds__(256, 1) void gemm_log_kernel(
        const unsigned short* __restrict__ A,   // S x K bf16, row-major
        const unsigned short* __restrict__ B,   // N x K bf16, row-major
        const float* __restrict__ lz,
        float* __restrict__ out) {
    __shared__ __align__(16) char lds[NBUF * TILE_BYTES];   // 128 KB
    const int tid  = threadIdx.x;
    const int l    = tid & 63;
    const int w    = tid >> 6;
    const int bn = blockIdx.x & 7;     // XCD-affine: same-XCD blocks share the 1MB B-panel
    const int bm = blockIdx.x >> 3;    // 0..31
    const int wr = w >> 1, wc = w & 1; // wave owns 64x64 quadrant
    const int lcol = l & 15, lk = l >> 4;

    // ---- staging (rule #21): linear LDS dest, pre-swizzled global source ----
    const int kg = (l & 3) ^ ((l >> 3) & 3);
    const unsigned short* src[4];
    int dst[4];
    #pragma unroll
    for (int i = 0; i < 4; ++i) {
        const int ri  = w * 4 + i;             // 16-row slab 0..15
        const int row = ri * 16 + (l >> 2);    // local row 0..255
        src[i] = (ri < 8)
            ? A + (size_t)(bm * BM + row) * K_DIM + kg * 8
            : B + (size_t)(bn * BN + row - 128) * K_DIM + kg * 8;
        dst[i] = row * 64 + (l & 3) * 16;      // == wave-uniform base + l*16
    }

    // ---- fragment read offsets (swizzled, loop-invariant) ----
    const int swz = (lk ^ ((lcol >> 1) & 3)) << 4;
    int aoff[4], boff[4];
    #pragma unroll
    for (int m = 0; m < 4; ++m) aoff[m] = (wr * 64 + m * 16 + lcol) * 64 + swz;
    #pragma unroll
    for (int n = 0; n < 4; ++n) boff[n] = 8192 + (wc * 64 + n * 16 + lcol) * 64 + swz;

    f32x4 acc[4][4] = {};
    bf16x8 a0[4], b0[4], a1[4], b1[4];         // two statically-named frag sets (rule #20)

#define GLOAD(p, o) __builtin_amdgcn_global_load_lds((gas_ptr)(const void*)(p), \
        (las_ptr)(void*)(lds + (o)), 16, 0, 0)
#define STAGE(T, BUFI) { const int _ko = (T) * BK; const int _bo = (BUFI) * TILE_BYTES; \
        GLOAD(src[0] + _ko, _bo + dst[0]); GLOAD(src[1] + _ko, _bo + dst[1]);           \
        GLOAD(src[2] + _ko, _bo + dst[2]); GLOAD(src[3] + _ko, _bo + dst[3]); }
#define READF(RBUF, AR, BR) { const char* _rb = lds + (RBUF) * TILE_BYTES;              \
        _Pragma("unroll") for (int m = 0; m < 4; ++m)                                   \
            AR[m] = *reinterpret_cast<const bf16x8*>(_rb + aoff[m]);                    \
        _Pragma("unroll") for (int n = 0; n < 4; ++n)                                   \
            BR[n] = *reinterpret_cast<const bf16x8*>(_rb + boff[n]); }
#define MFMAS(AMM, BMM)                                                                 \
        _Pragma("unroll") for (int m = 0; m < 4; ++m)                                   \
            _Pragma("unroll") for (int n = 0; n < 4; ++n)                               \
                acc[m][n] = __builtin_amdgcn_mfma_f32_16x16x32_bf16(AMM[m], BMM[n],     \
                                                                    acc[m][n], 0, 0, 0);
// Step T: ensure tile T+1 landed; barrier frees buf[T&7]; restage; read frags(T+1)
// into the spare set; MFMA on frags(T) read last step. MFMAs never wait on this
// step's ds_reads -> the per-step lgkmcnt lead-in is gone.
#define BODY(T, SB, RB, WAITN, DOSTAGE, AR, BR, AMM, BMM) {                             \
        asm volatile("s_waitcnt vmcnt(" #WAITN ")" ::: "memory");                       \
        __builtin_amdgcn_s_barrier();                                                   \
        if (DOSTAGE) STAGE((T) + 8, SB);                                                \
        READF(RB, AR, BR);                                                              \
        MFMAS(AMM, BMM); }

    // prologue: fill the ring, land tile 0, read its fragments
    STAGE(0, 0); STAGE(1, 1); STAGE(2, 2); STAGE(3, 3);
    STAGE(4, 4); STAGE(5, 5); STAGE(6, 6); STAGE(7, 7);
    asm volatile("s_waitcnt vmcnt(28)" ::: "memory");
    __builtin_amdgcn_s_barrier();
    READF(0, a0, b0);

    for (int t8 = 0; t8 < NT - 8; t8 += 8) {   // t = 0..119, compile-time buf/set indices
        BODY(t8 + 0, 0, 1, 24, 1, a1, b1, a0, b0);
        BODY(t8 + 1, 1, 2, 24, 1, a0, b0, a1, b1);
        BODY(t8 + 2, 2, 3, 24, 1, a1, b1, a0, b0);
        BODY(t8 + 3, 3, 4, 24, 1, a0, b0, a1, b1);
        BODY(t8 + 4, 4, 5, 24, 1, a1, b1, a0, b0);
        BODY(t8 + 5, 5, 6, 24, 1, a0, b0, a1, b1);
        BODY(t8 + 6, 6, 7, 24, 1, a1, b1, a0, b0);
        BODY(t8 + 7, 7, 0, 24, 1, a0, b0, a1, b1);
    }
    BODY(120, 0, 1, 24, 0, a1, b1, a0, b0);    // no more staging; drain counted
    BODY(121, 1, 2, 20, 0, a0, b0, a1, b1);
    BODY(122, 2, 3, 16, 0, a1, b1, a0, b0);
    BODY(123, 3, 4, 12, 0, a0, b0, a1, b1);
    BODY(124, 4, 5,  8, 0, a1, b1, a0, b0);
    BODY(125, 5, 6,  4, 0, a0, b0, a1, b1);
    BODY(126, 6, 7,  0, 0, a1, b1, a0, b0);
    MFMAS(a1, b1);                             // t = 127
#undef BODY
#undef MFMAS
#undef READF
#undef STAGE
#undef GLOAD

    // ---- epilogue: out = log(acc) - lz[col]; C/D: col=lane&15, row=(lane>>4)*4+j ----
    const int col_base = bn * BN + wc * 64;
    float lzv[4];
    #pragma unroll
    for (int n = 0; n < 4; ++n) lzv[n] = lz[col_base + n * 16 + lcol];
    #pragma unroll
    for (int m = 0; m < 4; ++m) {
        const int row0 = bm * BM + wr * 64 + m * 16 + lk * 4;
        #pragma unroll
        for (int n = 0; n < 4; ++n) {
            const int col = col_base + n * 16 + lcol;
            #pragma unroll
            for (int j = 0; j < 4; ++j)
                out[(size_t)(row0 + j) * N_DIM + col] = __logf(acc[m][n][j]) - lzv[n];
        }
    }
}

// ---------------- emergency fallback (no workspace) ----------------
__global__ void naive_kernel(const float* __restrict__ ll1, const float* __restrict__ ll2,
                             const float* __restrict__ w1, const float* __restrict__ w2,
                             float* __restrict__ out) {
    int idx = blockIdx.x * blockDim.x + threadIdx.x;
    if (idx >= S_DIM * N_DIM) return;
    int s = idx >> 10, n = idx & (N_DIM - 1);
    const float* a1 = ll1 + (size_t)s * C_DIM;
    const float* a2 = ll2 + (size_t)s * C_DIM;
    const float* b1 = w1 + (size_t)n * C_DIM;
    const float* b2 = w2 + (size_t)n * C_DIM;
    float mx = -3.0e38f;
    for (int c = 0; c < C_DIM; ++c) mx = fmaxf(mx, b1[c]);
    for (int c = 0; c < C_DIM; ++c) mx = fmaxf(mx, b2[c]);
    float zs = 0.f, acc = 0.f;
    for (int c = 0; c < C_DIM; ++c) { zs += __expf(b1[c] - mx); acc += __expf(a1[c] + b1[c]); }
    for (int c = 0; c < C_DIM; ++c) { zs += __expf(b2[c] - mx); acc += __expf(a2[c] + b2[c]); }
    out[idx] = __logf(acc) - (mx + __logf(zs));
}

extern "C" void kernel_launch(void* const* d_in, const int* in_sizes, int n_in,
                              void* d_out, int out_size, void* d_ws, size_t ws_size,
                              hipStream_t stream) {
    const float* ll1 = (const float*)d_in[0];
    const float* ll2 = (const float*)d_in[1];
    const float* w1  = (const float*)d_in[2];
    const float* w2  = (const float*)d_in[3];
    float* out = (float*)d_out;

    const size_t a_elems = (size_t)S_DIM * K_DIM;
    const size_t b_elems = (size_t)N_DIM * K_DIM;
    const size_t need = (a_elems + b_elems) * sizeof(unsigned short) + N_DIM * sizeof(float);
    if (ws_size < need) {
        naive_kernel<<<(S_DIM * N_DIM + 255) / 256, 256, 0, stream>>>(ll1, ll2, w1, w2, out);
        return;
    }
    unsigned short* Aws = (unsigned short*)d_ws;
    unsigned short* Bws = Aws + a_elems;
    float* lzws = (float*)(Bws + b_elems);

    exp_ll_kernel<<<2048, 256, 0, stream>>>(ll1, ll2, Aws);
    w_kernel<<<N_DIM, 256, 0, stream>>>(w1, w2, Bws, lzws);
    gemm_log_kernel<<<(S_DIM / BM) * (N_DIM / BN), 256, 0, stream>>>(Aws, Bws, lzws, out);
}

// Round 7
// 70.774 us; speedup vs baseline: 1.0038x; 1.0038x over previous
//
#include <hip/hip_runtime.h>

#define S_DIM 4096
#define C_DIM 2048      // C1 == C2
#define N_DIM 1024
#define K_DIM 4096      // C1 + C2

#define BM 128
#define BN 128
#define BK 32
#define NT (K_DIM / BK)         // 128 K-steps
#define TILE_BYTES 16384        // (128 A rows + 128 B rows) * 64 B
#define NBUF 8                  // 128 KB LDS ring

typedef __attribute__((ext_vector_type(8))) short bf16x8;
typedef __attribute__((ext_vector_type(4))) float f32x4;

__device__ static inline unsigned short f2bf(float f) {
    unsigned int u = __float_as_uint(f);
    u += 0x7FFFu + ((u >> 16) & 1u);
    return (unsigned short)(u >> 16);
}

// ---------------- exp + cast to bf16 for A (both ll sources, one launch) ----------------
__global__ void exp_ll_kernel(const float* __restrict__ ll1,
                              const float* __restrict__ ll2,
                              unsigned short* __restrict__ A) {
    const int total4 = S_DIM * C_DIM / 4;
    int stride = gridDim.x * blockDim.x;
    for (int i = blockIdx.x * blockDim.x + threadIdx.x; i < total4; i += stride) {
        int e = i << 2;
        int r = e >> 11;          // src cols = 2048
        int c = e & 2047;
        size_t dst = ((size_t)r << 12) + c;
        float4 v = *reinterpret_cast<const float4*>(ll1 + e);
        ushort4 o;
        o.x = f2bf(__expf(v.x)); o.y = f2bf(__expf(v.y));
        o.z = f2bf(__expf(v.z)); o.w = f2bf(__expf(v.w));
        *reinterpret_cast<ushort4*>(A + dst) = o;
        float4 u = *reinterpret_cast<const float4*>(ll2 + e);
        ushort4 p;
        p.x = f2bf(__expf(u.x)); p.y = f2bf(__expf(u.y));
        p.z = f2bf(__expf(u.z)); p.w = f2bf(__expf(u.w));
        *reinterpret_cast<ushort4*>(A + dst + C_DIM) = p;
    }
}

// ---------------- w: exp->B (bf16) AND per-row logsumexp, fused ----------------
__global__ void w_kernel(const float* __restrict__ w1,
                         const float* __restrict__ w2,
                         unsigned short* __restrict__ B,
                         float* __restrict__ lz) {
    const int n = blockIdx.x;
    const int tid = threadIdx.x;          // 0..255
    const int lane = tid & 63, wv = tid >> 6;
    const float* r1 = w1 + ((size_t)n << 11);
    const float* r2 = w2 + ((size_t)n << 11);
    float4 v0 = *reinterpret_cast<const float4*>(r1 + tid * 8);
    float4 v1 = *reinterpret_cast<const float4*>(r1 + tid * 8 + 4);
    float4 u0 = *reinterpret_cast<const float4*>(r2 + tid * 8);
    float4 u1 = *reinterpret_cast<const float4*>(r2 + tid * 8 + 4);

    float mx = fmaxf(fmaxf(fmaxf(v0.x, v0.y), fmaxf(v0.z, v0.w)),
                     fmaxf(fmaxf(v1.x, v1.y), fmaxf(v1.z, v1.w)));
    mx = fmaxf(mx, fmaxf(fmaxf(fmaxf(u0.x, u0.y), fmaxf(u0.z, u0.w)),
                          fmaxf(fmaxf(u1.x, u1.y), fmaxf(u1.z, u1.w))));
    #pragma unroll
    for (int off = 32; off > 0; off >>= 1) mx = fmaxf(mx, __shfl_xor(mx, off));
    __shared__ float red[4];
    if (lane == 0) red[wv] = mx;
    __syncthreads();
    mx = fmaxf(fmaxf(red[0], red[1]), fmaxf(red[2], red[3]));

    float s = __expf(v0.x - mx) + __expf(v0.y - mx) + __expf(v0.z - mx) + __expf(v0.w - mx)
            + __expf(v1.x - mx) + __expf(v1.y - mx) + __expf(v1.z - mx) + __expf(v1.w - mx)
            + __expf(u0.x - mx) + __expf(u0.y - mx) + __expf(u0.z - mx) + __expf(u0.w - mx)
            + __expf(u1.x - mx) + __expf(u1.y - mx) + __expf(u1.z - mx) + __expf(u1.w - mx);
    #pragma unroll
    for (int off = 32; off > 0; off >>= 1) s += __shfl_xor(s, off);
    __shared__ float red2[4];
    if (lane == 0) red2[wv] = s;
    __syncthreads();
    if (tid == 0)
        lz[n] = mx + __logf(red2[0] + red2[1] + red2[2] + red2[3]);

    unsigned short* brow = B + ((size_t)n << 12);
    ushort4 o;
    o.x = f2bf(__expf(v0.x)); o.y = f2bf(__expf(v0.y));
    o.z = f2bf(__expf(v0.z)); o.w = f2bf(__expf(v0.w));
    *reinterpret_cast<ushort4*>(brow + tid * 8) = o;
    o.x = f2bf(__expf(v1.x)); o.y = f2bf(__expf(v1.y));
    o.z = f2bf(__expf(v1.z)); o.w = f2bf(__expf(v1.w));
    *reinterpret_cast<ushort4*>(brow + tid * 8 + 4) = o;
    o.x = f2bf(__expf(u0.x)); o.y = f2bf(__expf(u0.y));
    o.z = f2bf(__expf(u0.z)); o.w = f2bf(__expf(u0.w));
    *reinterpret_cast<ushort4*>(brow + C_DIM + tid * 8) = o;
    o.x = f2bf(__expf(u1.x)); o.y = f2bf(__expf(u1.y));
    o.z = f2bf(__expf(u1.z)); o.w = f2bf(__expf(u1.w));
    *reinterpret_cast<ushort4*>(brow + C_DIM + tid * 8 + 4) = o;
}

// -- bf16 MFMA GEMM: producer/consumer waves, depth-8 ring, reg-frag pipeline, log-epilogue --
typedef const unsigned int __attribute__((address_space(1)))* gas_ptr;
typedef unsigned int __attribute__((address_space(3)))* las_ptr;

__global__ __launch_bounds__(512, 2) void gemm_log_kernel(
        const unsigned short* __restrict__ A,   // S x K bf16, row-major
        const unsigned short* __restrict__ B,   // N x K bf16, row-major
        const float* __restrict__ lz,
        float* __restrict__ out) {
    __shared__ __align__(16) char lds[NBUF * TILE_BYTES];   // 128 KB
    const int tid  = threadIdx.x;
    const int l    = tid & 63;
    const int w    = tid >> 6;         // 0..7: waves 0-3 consume, 4-7 produce
    const int bn = blockIdx.x & 7;     // XCD-affine: same-XCD blocks share the 1MB B-panel
    const int bm = blockIdx.x >> 3;    // 0..31

#define GLOAD(p_, o_) __builtin_amdgcn_global_load_lds((gas_ptr)(const void*)(p_), \
        (las_ptr)(void*)(lds + (o_)), 16, 0, 0)

    if (w >= 4) {
        // ================= PRODUCER waves =================
        const int pw = w - 4;                  // 0..3, stages slabs pw*4 .. pw*4+3
        const int kg = (l & 3) ^ ((l >> 3) & 3);   // pre-swizzled source chunk (rule #21)
        const unsigned short* src[4];
        int dst[4];
        #pragma unroll
        for (int i = 0; i < 4; ++i) {
            const int ri  = pw * 4 + i;            // 16-row slab 0..15
            const int row = ri * 16 + (l >> 2);    // local row 0..255
            src[i] = (ri < 8)
                ? A + (size_t)(bm * BM + row) * K_DIM + kg * 8
                : B + (size_t)(bn * BN + row - 128) * K_DIM + kg * 8;
            dst[i] = row * 64 + (l & 3) * 16;      // wave-uniform base + l*16
        }
#define STAGE(T, BUFI) { const int _ko = (T) * BK; const int _bo = (BUFI) * TILE_BYTES; \
        GLOAD(src[0] + _ko, _bo + dst[0]); GLOAD(src[1] + _ko, _bo + dst[1]);           \
        GLOAD(src[2] + _ko, _bo + dst[2]); GLOAD(src[3] + _ko, _bo + dst[3]); }
#define PBODY(T, BUFI, WAITN) {                                                         \
        asm volatile("s_waitcnt vmcnt(" #WAITN ")" ::: "memory");                       \
        __builtin_amdgcn_s_barrier();                                                   \
        STAGE((T) + 8, BUFI); }

        STAGE(0, 0); STAGE(1, 1); STAGE(2, 2); STAGE(3, 3);
        STAGE(4, 4); STAGE(5, 5); STAGE(6, 6); STAGE(7, 7);
        asm volatile("s_waitcnt vmcnt(28)" ::: "memory");   // tile 0 landed
        __builtin_amdgcn_s_barrier();                       // barrier #0
        for (int t8 = 0; t8 < NT - 8; t8 += 8) {            // T = 0..119
            PBODY(t8 + 0, 0, 24); PBODY(t8 + 1, 1, 24);
            PBODY(t8 + 2, 2, 24); PBODY(t8 + 3, 3, 24);
            PBODY(t8 + 4, 4, 24); PBODY(t8 + 5, 5, 24);
            PBODY(t8 + 6, 6, 24); PBODY(t8 + 7, 7, 24);
        }
        // drain: T = 120..126, no staging, counted vmcnt so consumers see each tile
        asm volatile("s_waitcnt vmcnt(24)" ::: "memory"); __builtin_amdgcn_s_barrier();
        asm volatile("s_waitcnt vmcnt(20)" ::: "memory"); __builtin_amdgcn_s_barrier();
        asm volatile("s_waitcnt vmcnt(16)" ::: "memory"); __builtin_amdgcn_s_barrier();
        asm volatile("s_waitcnt vmcnt(12)" ::: "memory"); __builtin_amdgcn_s_barrier();
        asm volatile("s_waitcnt vmcnt(8)"  ::: "memory"); __builtin_amdgcn_s_barrier();
        asm volatile("s_waitcnt vmcnt(4)"  ::: "memory"); __builtin_amdgcn_s_barrier();
        asm volatile("s_waitcnt vmcnt(0)"  ::: "memory"); __builtin_amdgcn_s_barrier();
        // total barriers: 1 + 120 + 7 = 128 (matches consumer)
#undef PBODY
#undef STAGE
    } else {
        // ================= CONSUMER waves =================
        const int wr = w >> 1, wc = w & 1;     // wave owns 64x64 quadrant
        const int lcol = l & 15, lk = l >> 4;
        const int swz = (lk ^ ((lcol >> 1) & 3)) << 4;
        int aoff[4], boff[4];
        #pragma unroll
        for (int m = 0; m < 4; ++m) aoff[m] = (wr * 64 + m * 16 + lcol) * 64 + swz;
        #pragma unroll
        for (int n = 0; n < 4; ++n) boff[n] = 8192 + (wc * 64 + n * 16 + lcol) * 64 + swz;

        f32x4 acc[4][4] = {};
        bf16x8 a0[4], b0[4], a1[4], b1[4];     // two statically-named frag sets (rule #20)

#define READF(RBUF, AR, BR) { const char* _rb = lds + (RBUF) * TILE_BYTES;              \
        _Pragma("unroll") for (int m = 0; m < 4; ++m)                                   \
            AR[m] = *reinterpret_cast<const bf16x8*>(_rb + aoff[m]);                    \
        _Pragma("unroll") for (int n = 0; n < 4; ++n)                                   \
            BR[n] = *reinterpret_cast<const bf16x8*>(_rb + boff[n]); }
#define MFMAS(AMM, BMM) {                                                               \
        __builtin_amdgcn_s_setprio(1);                                                  \
        _Pragma("unroll") for (int m = 0; m < 4; ++m)                                   \
            _Pragma("unroll") for (int n = 0; n < 4; ++n)                               \
                acc[m][n] = __builtin_amdgcn_mfma_f32_16x16x32_bf16(AMM[m], BMM[n],     \
                                                                    acc[m][n], 0, 0, 0);\
        __builtin_amdgcn_s_setprio(0); }
// Step T: barrier (producer vmcnt publishes tile T+1); read frags(T+1) into spare set;
// MFMA on frags(T). MFMAs never wait on this step's ds_reads.
#define CBODY(T, RB, AR, BR, AMM, BMM) {                                                \
        __builtin_amdgcn_s_barrier();                                                   \
        READF(RB, AR, BR);                                                              \
        MFMAS(AMM, BMM); }

        __builtin_amdgcn_s_barrier();          // barrier #0: tile 0 landed
        READF(0, a0, b0);
        for (int t8 = 0; t8 < NT - 8; t8 += 8) {   // T = 0..119
            CBODY(t8 + 0, 1, a1, b1, a0, b0);
            CBODY(t8 + 1, 2, a0, b0, a1, b1);
            CBODY(t8 + 2, 3, a1, b1, a0, b0);
            CBODY(t8 + 3, 4, a0, b0, a1, b1);
            CBODY(t8 + 4, 5, a1, b1, a0, b0);
            CBODY(t8 + 5, 6, a0, b0, a1, b1);
            CBODY(t8 + 6, 7, a1, b1, a0, b0);
            CBODY(t8 + 7, 0, a0, b0, a1, b1);
        }
        CBODY(120, 1, a1, b1, a0, b0);         // T = 120..126
        CBODY(121, 2, a0, b0, a1, b1);
        CBODY(122, 3, a1, b1, a0, b0);
        CBODY(123, 4, a0, b0, a1, b1);
        CBODY(124, 5, a1, b1, a0, b0);
        CBODY(125, 6, a0, b0, a1, b1);
        CBODY(126, 7, a1, b1, a0, b0);
        MFMAS(a1, b1);                         // T = 127
#undef CBODY
#undef MFMAS
#undef READF

        // ---- epilogue: out = log(acc) - lz[col]; C/D: col=lane&15, row=(lane>>4)*4+j ----
        const int col_base = bn * BN + wc * 64;
        float lzv[4];
        #pragma unroll
        for (int n = 0; n < 4; ++n) lzv[n] = lz[col_base + n * 16 + lcol];
        #pragma unroll
        for (int m = 0; m < 4; ++m) {
            const int row0 = bm * BM + wr * 64 + m * 16 + lk * 4;
            #pragma unroll
            for (int n = 0; n < 4; ++n) {
                const int col = col_base + n * 16 + lcol;
                #pragma unroll
                for (int j = 0; j < 4; ++j)
                    out[(size_t)(row0 + j) * N_DIM + col] = __logf(acc[m][n][j]) - lzv[n];
            }
        }
    }
#undef GLOAD
}

// ---------------- emergency fallback (no workspace) ----------------
__global__ void naive_kernel(const float* __restrict__ ll1, const float* __restrict__ ll2,
                             const float* __restrict__ w1, const float* __restrict__ w2,
                             float* __restrict__ out) {
    int idx = blockIdx.x * blockDim.x + threadIdx.x;
    if (idx >= S_DIM * N_DIM) return;
    int s = idx >> 10, n = idx & (N_DIM - 1);
    const float* a1 = ll1 + (size_t)s * C_DIM;
    const float* a2 = ll2 + (size_t)s * C_DIM;
    const float* b1 = w1 + (size_t)n * C_DIM;
    const float* b2 = w2 + (size_t)n * C_DIM;
    float mx = -3.0e38f;
    for (int c = 0; c < C_DIM; ++c) mx = fmaxf(mx, b1[c]);
    for (int c = 0; c < C_DIM; ++c) mx = fmaxf(mx, b2[c]);
    float zs = 0.f, acc = 0.f;
    for (int c = 0; c < C_DIM; ++c) { zs += __expf(b1[c] - mx); acc += __expf(a1[c] + b1[c]); }
    for (int c = 0; c < C_DIM; ++c) { zs += __expf(b2[c] - mx); acc += __expf(a2[c] + b2[c]); }
    out[idx] = __logf(acc) - (mx + __logf(zs));
}

extern "C" void kernel_launch(void* const* d_in, const int* in_sizes, int n_in,
                              void* d_out, int out_size, void* d_ws, size_t ws_size,
                              hipStream_t stream) {
    const float* ll1 = (const float*)d_in[0];
    const float* ll2 = (const float*)d_in[1];
    const float* w1  = (const float*)d_in[2];
    const float* w2  = (const float*)d_in[3];
    float* out = (float*)d_out;

    const size_t a_elems = (size_t)S_DIM * K_DIM;
    const size_t b_elems = (size_t)N_DIM * K_DIM;
    const size_t need = (a_elems + b_elems) * sizeof(unsigned short) + N_DIM * sizeof(float);
    if (ws_size < need) {
        naive_kernel<<<(S_DIM * N_DIM + 255) / 256, 256, 0, stream>>>(ll1, ll2, w1, w2, out);
        return;
    }
    unsigned short* Aws = (unsigned short*)d_ws;
    unsigned short* Bws = Aws + a_elems;
    float* lzws = (float*)(Bws + b_elems);

    exp_ll_kernel<<<2048, 256, 0, stream>>>(ll1, ll2, Aws);
    w_kernel<<<N_DIM, 256, 0, stream>>>(w1, w2, Bws, lzws);
    gemm_log_kernel<<<(S_DIM / BM) * (N_DIM / BN), 512, 0, stream>>>(Aws, Bws, lzws, out);
}